// Round 1
// baseline (240.752 us; speedup 1.0000x reference)
//
#include <hip/hip_runtime.h>
#include <hip/hip_bf16.h>

// GRU fused kernel for MI355X (gfx950). R6: single pixel-group per wave
// (16 px) -> 4096 waves -> 3 waves/SIMD for TLP on the serial recurrence;
// weight fragments hoisted to VGPRs (no steady-state LDS weight reads);
// log2e folded into staged weights/biases (exp2-direct gates);
// r/z hidden MFMAs C-chained onto input MFMAs (no G+H adds).
// T=24, N=65536 pixels, F=H=32, gates r,z,n (3H=96).
// gates^T(96x16) = W(96x32) @ x^T/h^T(32x16); one wave owns 16 pixels, 24 steps.

#define TSTEPS 24
#define NPIX 65536
#define PADW 40   // shorts per weight row in LDS (80 B) — breaks bank aliasing

typedef __attribute__((ext_vector_type(8))) short bf16x8;
typedef __attribute__((ext_vector_type(4))) float f32x4;
typedef __attribute__((ext_vector_type(4))) unsigned int u32x4;

#define MFMA16(a, b, c) __builtin_amdgcn_mfma_f32_16x16x32_bf16((a), (b), (c), 0, 0, 0)

#define SCL_RZ (-1.4426950408889634f)   // -log2(e): sigmoid(x) = rcp(1+exp2(-x*log2e))
#define SCL_N  ( 2.8853900817779268f)   // 2*log2(e): tanh(y) = 1-2*rcp(1+exp2(2y*log2e))

__device__ __forceinline__ unsigned short f2bf(float f) {
  unsigned u = __builtin_bit_cast(unsigned, f);
  u += 0x7fffu + ((u >> 16) & 1u);   // RNE (one-time staging only)
  return (unsigned short)(u >> 16);
}

// pack two f32 -> dword (bf16(a) low | bf16(b) high) via HW v_cvt_pk_bf16_f32
__device__ __forceinline__ unsigned pk2(float a, float b) {
  __hip_bfloat162 h = __float22bfloat162_rn(float2{a, b});
  unsigned u;
  __builtin_memcpy(&u, &h, sizeof(u));
  return u;
}

__device__ __forceinline__ bf16x8 pack8(f32x4 a, f32x4 b) {
  u32x4 r = { pk2(a[0], a[1]), pk2(a[2], a[3]), pk2(b[0], b[1]), pk2(b[2], b[3]) };
  return __builtin_bit_cast(bf16x8, r);
}

// sigmoid(x) given t = -x*log2e (scale folded into weights upstream)
__device__ __forceinline__ float sig2(float t) {
  return __builtin_amdgcn_rcpf(1.f + __builtin_amdgcn_exp2f(t));
}
// tanh(y) given t = 2y*log2e (scale folded into weights upstream)
__device__ __forceinline__ float tanh2(float t) {
  return 1.f - 2.f * __builtin_amdgcn_rcpf(1.f + __builtin_amdgcn_exp2f(t));
}

// h (two C-layout f32x4 tiles) -> B-layout bf16x8 fragment:
// pack row-pairs into dwords, 8 shuffles + 4 selects.
__device__ __forceinline__ bf16x8 relayout_h(const f32x4 h0, const f32x4 h1, int lane) {
  unsigned p00 = pk2(h0[0], h0[1]), p01 = pk2(h0[2], h0[3]);
  unsigned p10 = pk2(h1[0], h1[1]), p11 = pk2(h1[2], h1[3]);
  const int lo = (lane & 15) | ((lane & 16) << 1);   // col + (q&1)*32
  const int hi = lo + 16;
  unsigned a0 = (unsigned)__shfl((int)p00, lo, 64);
  unsigned a1 = (unsigned)__shfl((int)p01, lo, 64);
  unsigned a2 = (unsigned)__shfl((int)p00, hi, 64);
  unsigned a3 = (unsigned)__shfl((int)p01, hi, 64);
  unsigned b0 = (unsigned)__shfl((int)p10, lo, 64);
  unsigned b1 = (unsigned)__shfl((int)p11, lo, 64);
  unsigned b2 = (unsigned)__shfl((int)p10, hi, 64);
  unsigned b3 = (unsigned)__shfl((int)p11, hi, 64);
  const bool t1 = (lane & 32) != 0;                  // q >= 2 -> tile 1
  u32x4 d = { t1 ? b0 : a0, t1 ? b1 : a1, t1 ? b2 : a2, t1 ? b3 : a3 };
  return __builtin_bit_cast(bf16x8, d);
}

__global__ __launch_bounds__(256, 3)
void gru_fused(const float* __restrict__ spatial, const float* __restrict__ met,
               const float* __restrict__ ctx,
               const float* __restrict__ W_ih, const float* __restrict__ W_hh,
               const float* __restrict__ b_ih, const float* __restrict__ b_hh,
               const float* __restrict__ Wout, float* __restrict__ out) {
  // rows 0..95 = W_ih (scaled), rows 96..191 = W_hh (scaled); PADW-short stride
  __shared__ __align__(16) unsigned short sW[192 * PADW];
  __shared__ __align__(16) float sCB[64];   // (b_ih+b_hh)*SCL_RZ rows 0..63 (r,z)
  __shared__ __align__(16) float sBIN[32];  // b_ih*SCL_N rows 64..95 (n)
  __shared__ __align__(16) float sBHN[32];  // b_hh*SCL_N rows 64..95 (n)

  const int tid = threadIdx.x;
  for (int i = tid; i < 96 * 32; i += 256) {
    int r = i >> 5, c = i & 31;
    float s = (r < 64) ? SCL_RZ : SCL_N;
    sW[r * PADW + c] = f2bf(W_ih[i] * s);
    sW[(96 + r) * PADW + c] = f2bf(W_hh[i] * s);
  }
  if (tid < 64) sCB[tid] = (b_ih[tid] + b_hh[tid]) * SCL_RZ;
  else if (tid < 96) sBIN[tid - 64] = b_ih[tid] * SCL_N;
  else if (tid < 128) sBHN[tid - 96] = b_hh[tid - 32] * SCL_N;
  __syncthreads();

  const int lane = tid & 63;
  const int col = lane & 15;     // pixel column within group
  const int q = lane >> 4;       // k-quad
  const int wave = blockIdx.x * 4 + (tid >> 6);
  const long p0 = (long)wave * 16 + col;   // this wave's pixel

  // biases resident (read once from LDS), pre-scaled
  f32x4 cS[4];
#pragma unroll
  for (int i = 0; i < 4; ++i) cS[i] = *(const f32x4*)&sCB[i * 16 + q * 4];
  const f32x4 cG4 = *(const f32x4*)&sBIN[q * 4];
  const f32x4 cG5 = *(const f32x4*)&sBIN[16 + q * 4];
  const f32x4 cH4 = *(const f32x4*)&sBHN[q * 4];
  const f32x4 cH5 = *(const f32x4*)&sBHN[16 + q * 4];

  // weight fragments hoisted to registers once (loop-invariant)
  const int wb = col * PADW + q * 8;   // fragment base (shorts)
  const bf16x8 a0 = *(const bf16x8*)&sW[wb];
  const bf16x8 a1 = *(const bf16x8*)&sW[wb + 16 * PADW];
  const bf16x8 a2 = *(const bf16x8*)&sW[wb + 32 * PADW];
  const bf16x8 a3 = *(const bf16x8*)&sW[wb + 48 * PADW];
  const bf16x8 a4 = *(const bf16x8*)&sW[wb + 64 * PADW];
  const bf16x8 a5 = *(const bf16x8*)&sW[wb + 80 * PADW];
  const bf16x8 w0 = *(const bf16x8*)&sW[wb + 96 * PADW];
  const bf16x8 w1 = *(const bf16x8*)&sW[wb + 112 * PADW];
  const bf16x8 w2 = *(const bf16x8*)&sW[wb + 128 * PADW];
  const bf16x8 w3 = *(const bf16x8*)&sW[wb + 144 * PADW];
  const bf16x8 w4 = *(const bf16x8*)&sW[wb + 160 * PADW];
  const bf16x8 w5 = *(const bf16x8*)&sW[wb + 176 * PADW];

  // per-lane x stream (lane provides x^T[k=q*8+j][col])
  const float* xp0;
  long xstride;
  if (q < 2) {
    xp0 = spatial + p0 * 16 + q * 8;
    xstride = (long)NPIX * 16;
  } else if (q == 2) {
    xp0 = met + p0 * 8; xstride = (long)NPIX * 8;
  } else {
    xp0 = ctx + p0 * 8; xstride = (long)NPIX * 8;
  }

  bf16x8 bx = pack8(*(const f32x4*)xp0, *(const f32x4*)(xp0 + 4));
  xp0 += xstride;

  f32x4 h0a = {0.f, 0.f, 0.f, 0.f}, h0b = {0.f, 0.f, 0.f, 0.f};
  const f32x4 zero = {0.f, 0.f, 0.f, 0.f};

#pragma unroll 1
  for (int t = 0; t < TSTEPS; ++t) {
    // issue next step's x loads early (2 independent b128 loads)
    f32x4 xna, xnb;
    if (t < TSTEPS - 1) {
      xna = *(const f32x4*)xp0; xnb = *(const f32x4*)(xp0 + 4);
      xp0 += xstride;
    }

    // input-side MFMAs first (bx ready; fills MFMA pipe during the shuffles)
    f32x4 g0 = MFMA16(a0, bx, cS[0]);
    f32x4 g1 = MFMA16(a1, bx, cS[1]);
    f32x4 g2 = MFMA16(a2, bx, cS[2]);
    f32x4 g3 = MFMA16(a3, bx, cS[3]);
    f32x4 g4 = MFMA16(a4, bx, cG4);
    f32x4 g5 = MFMA16(a5, bx, cG5);

    // h -> B-layout
    bf16x8 bh = relayout_h(h0a, h0b, lane);

    // hidden-side MFMAs; r,z chained on input results (G+H add folded into C)
    f32x4 r0 = MFMA16(w0, bh, g0);
    f32x4 r1 = MFMA16(w1, bh, g1);
    f32x4 z0 = MFMA16(w2, bh, g2);
    f32x4 z1 = MFMA16(w3, bh, g3);
    f32x4 h4 = MFMA16(w4, bh, cH4);
    f32x4 h5 = MFMA16(w5, bh, cH5);

    // gate math: MFMA outputs are pre-scaled args for exp2-direct gates
#pragma unroll
    for (int r = 0; r < 4; ++r) {
      float ra = sig2(r0[r]);
      float rb = sig2(r1[r]);
      float za = sig2(z0[r]);
      float zb = sig2(z1[r]);
      float na = tanh2(__builtin_fmaf(ra, h4[r], g4[r]));
      float nb = tanh2(__builtin_fmaf(rb, h5[r], g5[r]));
      h0a[r] = na + za * (h0a[r] - na);
      h0b[r] = nb + zb * (h0b[r] - nb);
    }

    if (t < TSTEPS - 1) bx = pack8(xna, xnb);
  }

  // epilogue: out^T(16x16) = W^T(16x32) @ h^T(32x16)
  bf16x8 bhf = relayout_h(h0a, h0b, lane);
  float w[8];
#pragma unroll
  for (int j = 0; j < 8; ++j) w[j] = Wout[(q * 8 + j) * 16 + col];
  u32x4 awp = { pk2(w[0], w[1]), pk2(w[2], w[3]), pk2(w[4], w[5]), pk2(w[6], w[7]) };
  bf16x8 aw = __builtin_bit_cast(bf16x8, awp);
  f32x4 o0 = MFMA16(aw, bhf, zero);
  *(f32x4*)&out[p0 * 16 + q * 4] = o0;
}

extern "C" void kernel_launch(void* const* d_in, const int* in_sizes, int n_in,
                              void* d_out, int out_size, void* d_ws, size_t ws_size,
                              hipStream_t stream) {
  const float* spatial = (const float*)d_in[0];
  const float* met     = (const float*)d_in[1];
  const float* ctx     = (const float*)d_in[2];
  const float* W_ih    = (const float*)d_in[3];
  const float* W_hh    = (const float*)d_in[4];
  const float* b_ih    = (const float*)d_in[5];
  const float* b_hh    = (const float*)d_in[6];
  const float* Wout    = (const float*)d_in[7];
  float* out = (float*)d_out;

  // 4096 waves x 16 px; 1024 blocks of 256 -> up to 3 blocks/CU, 12 waves/CU
  gru_fused<<<dim3(NPIX / 16 / 4), dim3(256), 0, stream>>>(
      spatial, met, ctx, W_ih, W_hh, b_ih, b_hh, Wout, out);
}

// Round 2
// 230.342 us; speedup vs baseline: 1.0452x; 1.0452x over previous
//
#include <hip/hip_runtime.h>
#include <hip/hip_bf16.h>

// GRU fused kernel for MI355X (gfx950). R7: shuffle-free recurrence.
// Key idea: the hidden dimension is internal, so permute W_hh's columns
// (and W_out's rows) by tau(8q+j) = (j<4 ? 4q+j : 16+4q+(j-4)) at staging.
// Then the MFMA C-layout state tiles (h0a,h0b) concatenated lane-locally via
// pack8() ARE the next step's B-fragment: zero cross-lane ops per step.
// Dual pixel-group per wave (2 independent chains in-stream, R5's winning
// shape) + hoisted weight fragments in VGPRs + exp2-folded gates.
// T=24, N=65536 pixels, F=H=32, gates r,z,n (3H=96).
// gates^T(96x16) = W(96x32) @ x^T/h^T(32x16) per group; one wave = 32 px.

#define TSTEPS 24
#define NPIX 65536
#define PADW 40   // shorts per weight row in LDS (80 B) — breaks bank aliasing

typedef __attribute__((ext_vector_type(8))) short bf16x8;
typedef __attribute__((ext_vector_type(4))) float f32x4;
typedef __attribute__((ext_vector_type(4))) unsigned int u32x4;

#define MFMA16(a, b, c) __builtin_amdgcn_mfma_f32_16x16x32_bf16((a), (b), (c), 0, 0, 0)

#define SCL_RZ (-1.4426950408889634f)   // -log2(e): sigmoid(x) = rcp(1+exp2(-x*log2e))
#define SCL_N  ( 2.8853900817779268f)   // 2*log2(e): tanh(y) = 1-2*rcp(1+exp2(2y*log2e))

__device__ __forceinline__ unsigned short f2bf(float f) {
  unsigned u = __builtin_bit_cast(unsigned, f);
  u += 0x7fffu + ((u >> 16) & 1u);   // RNE (one-time staging only)
  return (unsigned short)(u >> 16);
}

// pack two f32 -> dword (bf16(a) low | bf16(b) high) via HW v_cvt_pk_bf16_f32
__device__ __forceinline__ unsigned pk2(float a, float b) {
  __hip_bfloat162 h = __float22bfloat162_rn(float2{a, b});
  unsigned u;
  __builtin_memcpy(&u, &h, sizeof(u));
  return u;
}

__device__ __forceinline__ bf16x8 pack8(f32x4 a, f32x4 b) {
  u32x4 r = { pk2(a[0], a[1]), pk2(a[2], a[3]), pk2(b[0], b[1]), pk2(b[2], b[3]) };
  return __builtin_bit_cast(bf16x8, r);
}

// sigmoid(x) given t = -x*log2e (scale folded into weights upstream)
__device__ __forceinline__ float sig2(float t) {
  return __builtin_amdgcn_rcpf(1.f + __builtin_amdgcn_exp2f(t));
}
// tanh(y) given t = 2y*log2e (scale folded into weights upstream)
__device__ __forceinline__ float tanh2(float t) {
  return 1.f - 2.f * __builtin_amdgcn_rcpf(1.f + __builtin_amdgcn_exp2f(t));
}

// tau: B-fragment k-slot -> state position (C-layout row), per 8-slot quad
__device__ __forceinline__ int tau(int k) {
  int q = k >> 3, j = k & 7;
  return (j < 4) ? (q * 4 + j) : (16 + q * 4 + (j - 4));
}

__global__ __launch_bounds__(256, 2)
void gru_fused(const float* __restrict__ spatial, const float* __restrict__ met,
               const float* __restrict__ ctx,
               const float* __restrict__ W_ih, const float* __restrict__ W_hh,
               const float* __restrict__ b_ih, const float* __restrict__ b_hh,
               const float* __restrict__ Wout, float* __restrict__ out) {
  // rows 0..95 = W_ih (scaled), rows 96..191 = W_hh (scaled, tau-permuted cols)
  __shared__ __align__(16) unsigned short sW[192 * PADW];
  __shared__ __align__(16) float sCB[64];   // (b_ih+b_hh)*SCL_RZ rows 0..63 (r,z)
  __shared__ __align__(16) float sBIN[32];  // b_ih*SCL_N rows 64..95 (n)
  __shared__ __align__(16) float sBHN[32];  // b_hh*SCL_N rows 64..95 (n)

  const int tid = threadIdx.x;
  for (int i = tid; i < 96 * 32; i += 256) {
    int r = i >> 5, c = i & 31;
    float s = (r < 64) ? SCL_RZ : SCL_N;
    sW[r * PADW + c] = f2bf(W_ih[i] * s);
    sW[(96 + r) * PADW + c] = f2bf(W_hh[r * 32 + tau(c)] * s);
  }
  if (tid < 64) sCB[tid] = (b_ih[tid] + b_hh[tid]) * SCL_RZ;
  else if (tid < 96) sBIN[tid - 64] = b_ih[tid] * SCL_N;
  else if (tid < 128) sBHN[tid - 96] = b_hh[tid - 32] * SCL_N;
  __syncthreads();

  const int lane = tid & 63;
  const int col = lane & 15;     // pixel column within group (also A-frag row)
  const int q = lane >> 4;       // k-quad
  const int wave = blockIdx.x * 4 + (tid >> 6);
  const long p0 = (long)wave * 32 + col;   // group 0 pixel
  const long p1 = p0 + 16;                 // group 1 pixel

  // biases resident (read once from LDS), pre-scaled
  f32x4 cS[4];
#pragma unroll
  for (int i = 0; i < 4; ++i) cS[i] = *(const f32x4*)&sCB[i * 16 + q * 4];
  const f32x4 cG4 = *(const f32x4*)&sBIN[q * 4];
  const f32x4 cG5 = *(const f32x4*)&sBIN[16 + q * 4];
  const f32x4 cH4 = *(const f32x4*)&sBHN[q * 4];
  const f32x4 cH5 = *(const f32x4*)&sBHN[16 + q * 4];

  // weight fragments hoisted to registers once (loop-invariant)
  const int wb = col * PADW + q * 8;   // fragment base (shorts)
  const bf16x8 a0 = *(const bf16x8*)&sW[wb];
  const bf16x8 a1 = *(const bf16x8*)&sW[wb + 16 * PADW];
  const bf16x8 a2 = *(const bf16x8*)&sW[wb + 32 * PADW];
  const bf16x8 a3 = *(const bf16x8*)&sW[wb + 48 * PADW];
  const bf16x8 a4 = *(const bf16x8*)&sW[wb + 64 * PADW];
  const bf16x8 a5 = *(const bf16x8*)&sW[wb + 80 * PADW];
  const bf16x8 w0 = *(const bf16x8*)&sW[wb + 96 * PADW];
  const bf16x8 w1 = *(const bf16x8*)&sW[wb + 112 * PADW];
  const bf16x8 w2 = *(const bf16x8*)&sW[wb + 128 * PADW];
  const bf16x8 w3 = *(const bf16x8*)&sW[wb + 144 * PADW];
  const bf16x8 w4 = *(const bf16x8*)&sW[wb + 160 * PADW];
  const bf16x8 w5 = *(const bf16x8*)&sW[wb + 176 * PADW];

  // per-lane x streams (lane provides x^T[k=q*8+j][col] for each group)
  const float *xp0, *xp1;
  long xstride;
  if (q < 2) {
    xp0 = spatial + p0 * 16 + q * 8; xp1 = spatial + p1 * 16 + q * 8;
    xstride = (long)NPIX * 16;
  } else if (q == 2) {
    xp0 = met + p0 * 8; xp1 = met + p1 * 8; xstride = (long)NPIX * 8;
  } else {
    xp0 = ctx + p0 * 8; xp1 = ctx + p1 * 8; xstride = (long)NPIX * 8;
  }

  bf16x8 bx0 = pack8(*(const f32x4*)xp0, *(const f32x4*)(xp0 + 4));
  bf16x8 bx1 = pack8(*(const f32x4*)xp1, *(const f32x4*)(xp1 + 4));
  xp0 += xstride; xp1 += xstride;

  f32x4 h0a = {0.f, 0.f, 0.f, 0.f}, h0b = {0.f, 0.f, 0.f, 0.f};   // group 0
  f32x4 h1a = {0.f, 0.f, 0.f, 0.f}, h1b = {0.f, 0.f, 0.f, 0.f};   // group 1
  const f32x4 zero = {0.f, 0.f, 0.f, 0.f};

#pragma unroll 1
  for (int t = 0; t < TSTEPS; ++t) {
    // issue next step's x loads early (4 independent b128 loads)
    f32x4 xn0a, xn0b, xn1a, xn1b;
    if (t < TSTEPS - 1) {
      xn0a = *(const f32x4*)xp0; xn0b = *(const f32x4*)(xp0 + 4);
      xn1a = *(const f32x4*)xp1; xn1b = *(const f32x4*)(xp1 + 4);
      xp0 += xstride; xp1 += xstride;
    }

    // h -> B-fragment: lane-local pack, zero shuffles (tau absorbed in W_hh)
    bf16x8 bh0 = pack8(h0a, h0b);
    bf16x8 bh1 = pack8(h1a, h1b);

    // input-side MFMAs (bx prefetched; fill the pipe)
    f32x4 G00 = MFMA16(a0, bx0, cS[0]);  f32x4 G10 = MFMA16(a0, bx1, cS[0]);
    f32x4 G01 = MFMA16(a1, bx0, cS[1]);  f32x4 G11 = MFMA16(a1, bx1, cS[1]);
    f32x4 G02 = MFMA16(a2, bx0, cS[2]);  f32x4 G12 = MFMA16(a2, bx1, cS[2]);
    f32x4 G03 = MFMA16(a3, bx0, cS[3]);  f32x4 G13 = MFMA16(a3, bx1, cS[3]);
    f32x4 G04 = MFMA16(a4, bx0, cG4);    f32x4 G14 = MFMA16(a4, bx1, cG4);
    f32x4 G05 = MFMA16(a5, bx0, cG5);    f32x4 G15 = MFMA16(a5, bx1, cG5);

    // hidden-side MFMAs; r,z chained on input results (G+H add folded into C)
    f32x4 R00 = MFMA16(w0, bh0, G00);    f32x4 R10 = MFMA16(w0, bh1, G10);
    f32x4 R01 = MFMA16(w1, bh0, G01);    f32x4 R11 = MFMA16(w1, bh1, G11);
    f32x4 Z00 = MFMA16(w2, bh0, G02);    f32x4 Z10 = MFMA16(w2, bh1, G12);
    f32x4 Z01 = MFMA16(w3, bh0, G03);    f32x4 Z11 = MFMA16(w3, bh1, G13);
    f32x4 H04 = MFMA16(w4, bh0, cH4);    f32x4 H14 = MFMA16(w4, bh1, cH4);
    f32x4 H05 = MFMA16(w5, bh0, cH5);    f32x4 H15 = MFMA16(w5, bh1, cH5);

    // gate math (exp2-direct, scales folded upstream), both groups interleaved
#pragma unroll
    for (int r = 0; r < 4; ++r) {
      float r00 = sig2(R00[r]);
      float r01 = sig2(R01[r]);
      float z00 = sig2(Z00[r]);
      float z01 = sig2(Z01[r]);
      float n00 = tanh2(__builtin_fmaf(r00, H04[r], G04[r]));
      float n01 = tanh2(__builtin_fmaf(r01, H05[r], G05[r]));
      h0a[r] = n00 + z00 * (h0a[r] - n00);
      h0b[r] = n01 + z01 * (h0b[r] - n01);

      float r10 = sig2(R10[r]);
      float r11 = sig2(R11[r]);
      float z10 = sig2(Z10[r]);
      float z11 = sig2(Z11[r]);
      float n10 = tanh2(__builtin_fmaf(r10, H14[r], G14[r]));
      float n11 = tanh2(__builtin_fmaf(r11, H15[r], G15[r]));
      h1a[r] = n10 + z10 * (h1a[r] - n10);
      h1b[r] = n11 + z11 * (h1b[r] - n11);
    }

    if (t < TSTEPS - 1) {
      bx0 = pack8(xn0a, xn0b);
      bx1 = pack8(xn1a, xn1b);
    }
  }

  // epilogue: out^T(16x16) = W^T(16x32) @ h^T(32x16) per group.
  // B-frag is the same tau-packed state, so Wout rows are read tau-permuted.
  bf16x8 bhf0 = pack8(h0a, h0b);
  bf16x8 bhf1 = pack8(h1a, h1b);
  float w[8];
#pragma unroll
  for (int j = 0; j < 8; ++j) {
    int tk = (j < 4) ? (q * 4 + j) : (16 + q * 4 + (j - 4));   // tau(q*8+j)
    w[j] = Wout[tk * 16 + col];
  }
  u32x4 awp = { pk2(w[0], w[1]), pk2(w[2], w[3]), pk2(w[4], w[5]), pk2(w[6], w[7]) };
  bf16x8 aw = __builtin_bit_cast(bf16x8, awp);
  f32x4 o0 = MFMA16(aw, bhf0, zero);
  f32x4 o1 = MFMA16(aw, bhf1, zero);
  *(f32x4*)&out[p0 * 16 + q * 4] = o0;
  *(f32x4*)&out[p1 * 16 + q * 4] = o1;
}

extern "C" void kernel_launch(void* const* d_in, const int* in_sizes, int n_in,
                              void* d_out, int out_size, void* d_ws, size_t ws_size,
                              hipStream_t stream) {
  const float* spatial = (const float*)d_in[0];
  const float* met     = (const float*)d_in[1];
  const float* ctx     = (const float*)d_in[2];
  const float* W_ih    = (const float*)d_in[3];
  const float* W_hh    = (const float*)d_in[4];
  const float* b_ih    = (const float*)d_in[5];
  const float* b_hh    = (const float*)d_in[6];
  const float* Wout    = (const float*)d_in[7];
  float* out = (float*)d_out;

  // 2048 waves x 32 px; 512 blocks of 256 = 2 blocks/CU, 8 waves/CU
  gru_fused<<<dim3(NPIX / 32 / 4), dim3(256), 0, stream>>>(
      spatial, met, ctx, W_ih, W_hh, b_ih, b_hh, Wout, out);
}